// Round 12
// baseline (40.286 us; speedup 1.0000x reference)
//
#include <hip/hip_runtime.h>
#include <math.h>

#define BATCH 32
#define M 64
#define R 8
typedef unsigned long long u64;
typedef unsigned int u32;

// XOR swizzle of the float4 slot within a 64-float (256 B) LDS row (G4 recipe).
#define SWZ_SLOT(r, s) ((s) ^ ((r) & 7))
#define PM_IDX(r, c) ((((r) << 6)) + ((SWZ_SLOT((r), (c) >> 2) << 2) | ((c) & 3)))

#define NSLOT 33   // 32 folded strict-lower slots + 1 diagonal slot per lane

__device__ __forceinline__ u32 umax2(u32 a, u32 b) { return a > b ? a : b; }
__device__ __forceinline__ u32 umax3(u32 a, u32 b, u32 c) {
    return umax2(umax2(a, b), c);                    // fuses to v_max3_u32
}

// Monotone f32 -> u32 map (order-preserving, total).
__device__ __forceinline__ u32 sortable(float f) {
    const u32 u = __float_as_uint(f);
    return u ^ ((u32)(((int)u) >> 31) | 0x80000000u);
}
// Inverse (low 12 bits unknown; caller passes bucket midpoint).
__device__ __forceinline__ float unsortable(u32 k) {
    const u32 fb = (k & 0x80000000u) ? (k ^ 0x80000000u) : ~k;
    return __uint_as_float(fb);
}

// sign-extended bit j of w: 0xFFFFFFFF if set, else 0 (v_bfe_i32).
#define SEXTBIT(w, j) ((u32)(((int)((w) << (31 - (j)))) >> 31))

// Wave-wide u32 max: 3 max3-windowed DPP steps (16-lane rows) + 4 readlanes
// + scalar max tree. old=src, bound_ctrl=false => invalid lanes self-max.
__device__ __forceinline__ u32 wave_umax_scalar(u32 g) {
    int v = (int)g;
    const int s1a = __builtin_amdgcn_update_dpp(v, v, 0x111, 0xf, 0xf, false); // shr1
    const int s1b = __builtin_amdgcn_update_dpp(v, v, 0x112, 0xf, 0xf, false); // shr2
    const u32 t1 = umax3(g, (u32)s1a, (u32)s1b);                // window 3
    const int w = (int)t1;
    const int s2a = __builtin_amdgcn_update_dpp(w, w, 0x113, 0xf, 0xf, false); // shr3
    const int s2b = __builtin_amdgcn_update_dpp(w, w, 0x116, 0xf, 0xf, false); // shr6
    const u32 t2 = umax3(t1, (u32)s2a, (u32)s2b);               // window 9
    const int y = (int)t2;
    const int s3 = __builtin_amdgcn_update_dpp(y, y, 0x117, 0xf, 0xf, false);  // shr7
    const u32 t3 = umax2(t2, (u32)s3);                          // window 16
    const u32 a = (u32)__builtin_amdgcn_readlane((int)t3, 15);
    const u32 b = (u32)__builtin_amdgcn_readlane((int)t3, 31);
    const u32 c = (u32)__builtin_amdgcn_readlane((int)t3, 47);
    const u32 d = (u32)__builtin_amdgcn_readlane((int)t3, 63);
    return umax2(umax2(a, b), umax2(c, d));                     // scalar s_max
}

__device__ __forceinline__ u64 readlane_u64(u64 v, int lane) {
    unsigned lo = (unsigned)__builtin_amdgcn_readlane((int)(unsigned)v, lane);
    unsigned hi = (unsigned)__builtin_amdgcn_readlane((int)(v >> 32), lane);
    return ((u64)hi << 32) | lo;
}

// masked main-slot leaf (slot j in 0..31, alive word).
#define KM(j) (q##j & SEXTBIT(alive, j))
#define T1G(n, A, B, C2) const u32 a##n = umax3(KM(A), KM(B), KM(C2));
#define LOADK(k) const u32 q##k = fold_lds[fbase + (k)];

// One block per batch. 4 waves: stage pairmax into LDS, fold the lower
// triangle into self-identifying per-lane keys [64][33]; wave 0 runs the
// greedy loop on 33 register keys/lane with a single alive-mask word; wave 1
// computes the label score into LDS. One atomicAdd per block -> d_out.
__global__ __launch_bounds__(256)
__attribute__((amdgpu_waves_per_eu(1, 1)))
void tree_crf_mst_kernel(const float* __restrict__ le,   // [B, M, M, R]
                         const int* __restrict__ tree,   // [B, M, 3]
                         float* __restrict__ out)        // [1], pre-zeroed
{
    __shared__ __align__(16) float pm[M * M];            // 16 KB swizzled rows
    __shared__ u32 fold_lds[M * NSLOT];                  // 8.25 KB folded keys
    __shared__ float ls_sh;                              // label score handoff
    const int b = blockIdx.x;
    const int tt = threadIdx.x;
    const float* bl = le + (size_t)b * M * M * R;
    const float4* g4 = reinterpret_cast<const float4*>(bl);

    // ---- stage pairmax[r][c] = max_k le[r,c,k] (all 4 waves, coalesced) ----
    for (int q = tt; q < M * M; q += 256) {
        const float4 a  = g4[2 * q];
        const float4 c4 = g4[2 * q + 1];
        const float mx = fmaxf(fmaxf(fmaxf(a.x, a.y), fmaxf(a.z, a.w)),
                               fmaxf(fmaxf(c4.x, c4.y), fmaxf(c4.z, c4.w)));
        const int rr = q >> 6, cc = q & 63;
        pm[PM_IDX(rr, cc)] = mx;
    }
    __syncthreads();

    // ---- pre-fold: key{r,c} = max over both directions, self-identifying ----
    // lane layout: s=lane>>1; even: rowB=63-s cols 0..31; odd: rowB cols
    // 32..62-s then rowA=s cols 0..s-1; slot 32 = diagonal (lane,lane).
    for (int S = tt; S < M * NSLOT; S += 256) {
        const int k = S >> 6, lane = S & 63;
        const int s = lane >> 1, e = lane & 1;
        int r, c; bool valid = true;
        if (k == 32)      { r = lane; c = lane; }
        else if (!e)      { r = 63 - s; c = k; }
        else if (k <= 30 - s) { r = 63 - s; c = 32 + k; }
        else if (k <= 30) { r = s; c = k - (31 - s); }
        else              { r = 0; c = 0; valid = false; }
        u32 key = 0;
        if (valid) {
            const u32 v = umax2(sortable(pm[PM_IDX(r, c)]),
                                sortable(pm[PM_IDX(c, r)]));
            key = (v & 0xFFFFF000u) | ((u32)(63 - r) << 6) | (u32)(63 - c);
        }
        fold_lds[lane * NSLOT + k] = key;
    }
    __syncthreads();

    const int wave = tt >> 6;
    const int t = tt & 63;
    float mst = 0.0f;

    if (wave == 1) {
        // ---- label tree score (overlaps wave 0's greedy loop) ----
        const int* tr = tree + ((size_t)b * M + t) * 3;
        const int i0 = tr[0], i1 = tr[1], i2 = tr[2];
        float ls = 0.0f;
        if (!((i0 == 0) & (i1 == 0) & (i2 == 0)))        // (0,0,0) contributes 0
            ls = bl[(size_t)((i0 << 6) | i1) * R + i2];
        #pragma unroll
        for (int off = 32; off; off >>= 1) ls += __shfl_down(ls, off);
        if (t == 0) ls_sh = ls;
    }

    if (wave == 0) {
        // ---- lane t: 33 folded keys as named registers (loop-invariant) ----
        const int fbase = t * NSLOT;
        LOADK(0)  LOADK(1)  LOADK(2)  LOADK(3)  LOADK(4)  LOADK(5)
        LOADK(6)  LOADK(7)  LOADK(8)  LOADK(9)  LOADK(10) LOADK(11)
        LOADK(12) LOADK(13) LOADK(14) LOADK(15) LOADK(16) LOADK(17)
        LOADK(18) LOADK(19) LOADK(20) LOADK(21) LOADK(22) LOADK(23)
        LOADK(24) LOADK(25) LOADK(26) LOADK(27) LOADK(28) LOADK(29)
        LOADK(30) LOADK(31) LOADK(32)

        const int s  = t >> 1;
        const int eO = t & 1;                            // odd-lane flag
        const int rB = 63 - s, rA = s;
        const int shA = 31 - s;
        const u32 maskC = (1u << (31 - s)) - 1u;         // odd: row-B hi cols
        const u32 maskA = (1u << s) - 1u;                // odd: row-A cols
        const u64 lanebit = 1ull << t;

        u64 mask = lanebit;                              // partition of node t
        u32 alive = 0xFFFFFFFFu;                         // main slots 0..31
        u32 dmask = 0xFFFFFFFFu;                         // diagonal alive mask

        #pragma unroll 1                                 // keep loop rolled
        for (int it = 0; it < M; ++it) {
            // ---- masked row max: 2-op leaves + v_max3_u32 tree ----
            T1G(0,0,1,2)    T1G(1,3,4,5)    T1G(2,6,7,8)    T1G(3,9,10,11)
            T1G(4,12,13,14) T1G(5,15,16,17) T1G(6,18,19,20) T1G(7,21,22,23)
            T1G(8,24,25,26) T1G(9,27,28,29)
            const u32 a10 = umax3(KM(30), KM(31), q32 & dmask);
            const u32 b0 = umax3(a0, a1, a2);
            const u32 b1 = umax3(a3, a4, a5);
            const u32 b2 = umax3(a6, a7, a8);
            const u32 b3 = umax2(a9, a10);
            const u32 rowmax = umax3(umax2(b0, b1), b2, b3);

            // ---- global max: key alone identifies winner pair {gi, gj} ----
            const u32 gv = wave_umax_scalar(rowmax);     // uniform
            const int gi = 63 - (int)((gv >> 6) & 63u);
            const int gj = 63 - (int)(gv & 63u);
            const u64 mf = readlane_u64(mask, gi);
            const u64 mt = readlane_u64(mask, gj);

            // ---- blocking first (gates next iteration's leaves) ----
            const u32 bBP = (u32)(mf >> rB) & 1u, bBQ = (u32)(mt >> rB) & 1u;
            const u64 rbB = (bBP ? mt : 0ull) | (bBQ ? mf : 0ull);
            const u32 bAP = (u32)(mf >> rA) & 1u, bAQ = (u32)(mt >> rA) & 1u;
            const u32 rbA = (bAP ? (u32)mt : 0u) | (bAQ ? (u32)mf : 0u);
            const u32 kOdd = (((u32)(rbB >> 32)) & maskC) |
                             ((rbA & maskA) << shA);
            const u32 kslots = eO ? kOdd : (u32)rbB;
            alive &= ~kslots;
            if (gi == gj) {                              // rare uniform branch:
                const u32 inP = (u32)(mf >> t) & 1u;     // self-pick kills the
                dmask &= (inP - 1u);                     // partition's diagonals
            }

            // ---- off-chain: energy + partition merge ----
            mst += unsortable((gv & 0xFFFFF000u) | 0x800u);
            const u64 merged = mf | mt;
            if (merged & lanebit) mask = merged;
        }
    }

    __syncthreads();                                     // all 4 waves arrive
    if (wave == 0 && t == 0)
        atomicAdd(out, (mst - ls_sh) * (1.0f / BATCH));
}

extern "C" void kernel_launch(void* const* d_in, const int* in_sizes, int n_in,
                              void* d_out, int out_size, void* d_ws, size_t ws_size,
                              hipStream_t stream) {
    const float* le   = (const float*)d_in[0];   // [32, 64, 64, 8] f32
    const int*   tree = (const int*)d_in[1];     // [32, 64, 3] i32
    float* out = (float*)d_out;                  // [1] f32

    // Zero the accumulator each call (stream op -> graph-capturable).
    hipMemsetAsync(out, 0, sizeof(float), stream);
    tree_crf_mst_kernel<<<BATCH, 256, 0, stream>>>(le, tree, out);
}

// Round 13
// 37.187 us; speedup vs baseline: 1.0833x; 1.0833x over previous
//
#include <hip/hip_runtime.h>
#include <math.h>

#define BATCH 32
#define M 64
#define R 8
typedef unsigned long long u64;
typedef unsigned int u32;

// XOR swizzle of the float4 slot within a 64-float (256 B) LDS row (G4 recipe).
#define SWZ_SLOT(r, s) ((s) ^ ((r) & 7))
#define PM_IDX(r, c) ((((r) << 6)) + ((SWZ_SLOT((r), (c) >> 2) << 2) | ((c) & 3)))

#define NSLOT 33   // 32 folded strict-lower slots + 1 diagonal slot per lane

__device__ __forceinline__ u32 umax2(u32 a, u32 b) { return a > b ? a : b; }
__device__ __forceinline__ u32 umax3(u32 a, u32 b, u32 c) {
    return umax2(umax2(a, b), c);                    // fuses to v_max3_u32
}

// Monotone f32 -> u32 map (order-preserving, total).
__device__ __forceinline__ u32 sortable(float f) {
    const u32 u = __float_as_uint(f);
    return u ^ ((u32)(((int)u) >> 31) | 0x80000000u);
}
// Inverse (low 12 bits unknown; caller passes bucket midpoint).
__device__ __forceinline__ float unsortable(u32 k) {
    const u32 fb = (k & 0x80000000u) ? (k ^ 0x80000000u) : ~k;
    return __uint_as_float(fb);
}

// sign-extended bit j of w: 0xFFFFFFFF if set, else 0 (v_bfe_i32).
#define SEXTBIT(w, j) ((u32)(((int)((w) << (31 - (j)))) >> 31))

// Wave-wide u32 max: 3 max3-windowed DPP steps (16-lane rows) + 4 readlanes
// + scalar max tree. old=src, bound_ctrl=false => invalid lanes self-max.
__device__ __forceinline__ u32 wave_umax_scalar(u32 g) {
    int v = (int)g;
    const int s1a = __builtin_amdgcn_update_dpp(v, v, 0x111, 0xf, 0xf, false); // shr1
    const int s1b = __builtin_amdgcn_update_dpp(v, v, 0x112, 0xf, 0xf, false); // shr2
    const u32 t1 = umax3(g, (u32)s1a, (u32)s1b);                // window 3
    const int w = (int)t1;
    const int s2a = __builtin_amdgcn_update_dpp(w, w, 0x113, 0xf, 0xf, false); // shr3
    const int s2b = __builtin_amdgcn_update_dpp(w, w, 0x116, 0xf, 0xf, false); // shr6
    const u32 t2 = umax3(t1, (u32)s2a, (u32)s2b);               // window 9
    const int y = (int)t2;
    const int s3 = __builtin_amdgcn_update_dpp(y, y, 0x117, 0xf, 0xf, false);  // shr7
    const u32 t3 = umax2(t2, (u32)s3);                          // window 16
    const u32 a = (u32)__builtin_amdgcn_readlane((int)t3, 15);
    const u32 b = (u32)__builtin_amdgcn_readlane((int)t3, 31);
    const u32 c = (u32)__builtin_amdgcn_readlane((int)t3, 47);
    const u32 d = (u32)__builtin_amdgcn_readlane((int)t3, 63);
    return umax2(umax2(a, b), umax2(c, d));                     // scalar s_max
}

__device__ __forceinline__ u64 readlane_u64(u64 v, int lane) {
    unsigned lo = (unsigned)__builtin_amdgcn_readlane((int)(unsigned)v, lane);
    unsigned hi = (unsigned)__builtin_amdgcn_readlane((int)(v >> 32), lane);
    return ((u64)hi << 32) | lo;
}

// masked main-slot leaf (slot j in 0..31, alive word).
#define KM(j) (q##j & SEXTBIT(alive, j))
#define T1G(n, A, B, C2) const u32 a##n = umax3(KM(A), KM(B), KM(C2));
#define LOADK(k) const u32 q##k = fold_lds[fbase + (k)];

// One block per batch. 4 waves: stage pairmax into LDS, fold the lower
// triangle into self-identifying per-lane keys [64][33]; wave 0 runs the
// greedy loop on 33 register keys/lane with a single alive-mask word; wave 1
// computes the label score concurrently; waves 2-3 retire after folding.
__global__ __launch_bounds__(256)
__attribute__((amdgpu_waves_per_eu(1, 1)))
void tree_crf_mst_kernel(const float* __restrict__ le,   // [B, M, M, R]
                         const int* __restrict__ tree,   // [B, M, 3]
                         float* __restrict__ mst_out,    // [B]
                         float* __restrict__ ls_out)     // [B]
{
    __shared__ __align__(16) float pm[M * M];            // 16 KB swizzled rows
    __shared__ u32 fold_lds[M * NSLOT];                  // 8.25 KB folded keys
    const int b = blockIdx.x;
    const int tt = threadIdx.x;
    const float* bl = le + (size_t)b * M * M * R;
    const float4* g4 = reinterpret_cast<const float4*>(bl);

    // ---- stage pairmax[r][c] = max_k le[r,c,k] (all 4 waves, coalesced) ----
    for (int q = tt; q < M * M; q += 256) {
        const float4 a  = g4[2 * q];
        const float4 c4 = g4[2 * q + 1];
        const float mx = fmaxf(fmaxf(fmaxf(a.x, a.y), fmaxf(a.z, a.w)),
                               fmaxf(fmaxf(c4.x, c4.y), fmaxf(c4.z, c4.w)));
        const int rr = q >> 6, cc = q & 63;
        pm[PM_IDX(rr, cc)] = mx;
    }
    __syncthreads();

    // ---- pre-fold: key{r,c} = max over both directions, self-identifying ----
    // lane layout: s=lane>>1; even: rowB=63-s cols 0..31; odd: rowB cols
    // 32..62-s then rowA=s cols 0..s-1; slot 32 = diagonal (lane,lane).
    for (int S = tt; S < M * NSLOT; S += 256) {
        const int k = S >> 6, lane = S & 63;
        const int s = lane >> 1, e = lane & 1;
        int r, c; bool valid = true;
        if (k == 32)      { r = lane; c = lane; }
        else if (!e)      { r = 63 - s; c = k; }
        else if (k <= 30 - s) { r = 63 - s; c = 32 + k; }
        else if (k <= 30) { r = s; c = k - (31 - s); }
        else              { r = 0; c = 0; valid = false; }
        u32 key = 0;
        if (valid) {
            const u32 v = umax2(sortable(pm[PM_IDX(r, c)]),
                                sortable(pm[PM_IDX(c, r)]));
            key = (v & 0xFFFFF000u) | ((u32)(63 - r) << 6) | (u32)(63 - c);
        }
        fold_lds[lane * NSLOT + k] = key;
    }
    __syncthreads();

    const int wave = tt >> 6;
    const int t = tt & 63;

    if (wave == 1) {
        // ---- label tree score (overlaps wave 0's greedy loop) ----
        const int* tr = tree + ((size_t)b * M + t) * 3;
        const int i0 = tr[0], i1 = tr[1], i2 = tr[2];
        float ls = 0.0f;
        if (!((i0 == 0) & (i1 == 0) & (i2 == 0)))        // (0,0,0) contributes 0
            ls = bl[(size_t)((i0 << 6) | i1) * R + i2];
        #pragma unroll
        for (int off = 32; off; off >>= 1) ls += __shfl_down(ls, off);
        if (t == 0) ls_out[b] = ls;
        return;
    }
    if (wave != 0) return;

    // ---- lane t: 33 folded keys as named registers (loop-invariant) ----
    const int fbase = t * NSLOT;
    LOADK(0)  LOADK(1)  LOADK(2)  LOADK(3)  LOADK(4)  LOADK(5)
    LOADK(6)  LOADK(7)  LOADK(8)  LOADK(9)  LOADK(10) LOADK(11)
    LOADK(12) LOADK(13) LOADK(14) LOADK(15) LOADK(16) LOADK(17)
    LOADK(18) LOADK(19) LOADK(20) LOADK(21) LOADK(22) LOADK(23)
    LOADK(24) LOADK(25) LOADK(26) LOADK(27) LOADK(28) LOADK(29)
    LOADK(30) LOADK(31) LOADK(32)

    const int s  = t >> 1;
    const int eO = t & 1;                                // odd-lane flag
    const int rB = 63 - s, rA = s;
    const int shA = 31 - s;
    const u32 maskC = (1u << (31 - s)) - 1u;             // odd: row-B hi cols
    const u32 maskA = (1u << s) - 1u;                    // odd: row-A cols
    const u64 lanebit = 1ull << t;

    u64 mask = lanebit;                                  // partition of node t
    u32 alive = 0xFFFFFFFFu;                             // main slots 0..31
    u32 dmask = 0xFFFFFFFFu;                             // diagonal alive mask
    float mst = 0.0f;

    #pragma unroll 1                                     // keep loop rolled
    for (int it = 0; it < M; ++it) {
        // ---- masked row max: 2-op leaves + v_max3_u32 tree ----
        T1G(0,0,1,2)    T1G(1,3,4,5)    T1G(2,6,7,8)    T1G(3,9,10,11)
        T1G(4,12,13,14) T1G(5,15,16,17) T1G(6,18,19,20) T1G(7,21,22,23)
        T1G(8,24,25,26) T1G(9,27,28,29)
        const u32 a10 = umax3(KM(30), KM(31), q32 & dmask);
        const u32 b0 = umax3(a0, a1, a2);
        const u32 b1 = umax3(a3, a4, a5);
        const u32 b2 = umax3(a6, a7, a8);
        const u32 b3 = umax2(a9, a10);
        const u32 rowmax = umax3(umax2(b0, b1), b2, b3);

        // ---- global max: key alone identifies winner pair {gi, gj} ----
        const u32 gv = wave_umax_scalar(rowmax);         // uniform
        const int gi = 63 - (int)((gv >> 6) & 63u);
        const int gj = 63 - (int)(gv & 63u);
        const u64 mf = readlane_u64(mask, gi);
        const u64 mt = readlane_u64(mask, gj);

        // ---- blocking first (gates next iteration's leaves) ----
        const u32 bBP = (u32)(mf >> rB) & 1u, bBQ = (u32)(mt >> rB) & 1u;
        const u64 rbB = (bBP ? mt : 0ull) | (bBQ ? mf : 0ull);
        const u32 bAP = (u32)(mf >> rA) & 1u, bAQ = (u32)(mt >> rA) & 1u;
        const u32 rbA = (bAP ? (u32)mt : 0u) | (bAQ ? (u32)mf : 0u);
        const u32 kOdd = (((u32)(rbB >> 32)) & maskC) | ((rbA & maskA) << shA);
        const u32 kslots = eO ? kOdd : (u32)rbB;
        alive &= ~kslots;
        if (gi == gj) {                                  // rare uniform branch:
            const u32 inP = (u32)(mf >> t) & 1u;         // self-pick kills the
            dmask &= (inP - 1u);                         // partition's diagonals
        }

        // ---- off-chain: energy + partition merge ----
        mst += unsortable((gv & 0xFFFFF000u) | 0x800u);
        const u64 merged = mf | mt;
        if (merged & lanebit) mask = merged;
    }
    if (t == 0) mst_out[b] = mst;
}

// Fixed-order final reduction -> deterministic scalar output.
__global__ void tree_crf_reduce_kernel(const float* __restrict__ mst_p,
                                       const float* __restrict__ ls_p,
                                       float* __restrict__ out)
{
    if (threadIdx.x == 0 && blockIdx.x == 0) {
        float s = 0.0f;
        for (int i = 0; i < BATCH; ++i) s += mst_p[i] - ls_p[i];
        out[0] = s * (1.0f / BATCH);
    }
}

extern "C" void kernel_launch(void* const* d_in, const int* in_sizes, int n_in,
                              void* d_out, int out_size, void* d_ws, size_t ws_size,
                              hipStream_t stream) {
    const float* le   = (const float*)d_in[0];   // [32, 64, 64, 8] f32
    const int*   tree = (const int*)d_in[1];     // [32, 64, 3] i32
    float* out = (float*)d_out;                  // [1] f32
    float* mst_p = (float*)d_ws;                 // [32]
    float* ls_p  = mst_p + BATCH;                // [32]

    tree_crf_mst_kernel<<<BATCH, 256, 0, stream>>>(le, tree, mst_p, ls_p);
    tree_crf_reduce_kernel<<<1, 64, 0, stream>>>(mst_p, ls_p, out);
}